// Round 1
// baseline (43.217 us; speedup 1.0000x reference)
//
#include <hip/hip_runtime.h>

#define COLS     65536
#define THREADS  1024
#define K_RANK   58981u          /* floor(0.9 * (COLS-1)); frac = 0.5 exactly */
#define CAPMAX   8192
#define LO_F     1.15f
#define HI_F     1.45f

__device__ __forceinline__ unsigned key_of(float x) {
    unsigned b = __float_as_uint(x);
    return (b & 0x80000000u) ? ~b : (b | 0x80000000u);
}
__device__ __forceinline__ float float_of_key(unsigned u) {
    unsigned b = (u & 0x80000000u) ? (u & 0x7FFFFFFFu) : ~u;
    return __uint_as_float(b);
}
__device__ __forceinline__ float wredF(float v) {
    #pragma unroll
    for (int o = 32; o > 0; o >>= 1) v += __shfl_down(v, o);
    return v;
}
__device__ __forceinline__ unsigned wredU(unsigned v) {
    #pragma unroll
    for (int o = 32; o > 0; o >>= 1) v += __shfl_down(v, o);
    return v;
}
__device__ __forceinline__ unsigned wredMinU(unsigned v) {
    #pragma unroll
    for (int o = 32; o > 0; o >>= 1) { unsigned n = __shfl_down(v, o); v = (n < v) ? n : v; }
    return v;
}

__global__ __launch_bounds__(THREADS)
void dtp_kernel(const float* __restrict__ X, float* __restrict__ out) {
    const int row  = blockIdx.x;
    const int tid  = threadIdx.x;
    const int lane = tid & 63;
    const int wid  = tid >> 6;
    const float4* x4 = (const float4*)(X + (size_t)row * COLS);

    __shared__ float    cap[CAPMAX];
    __shared__ float    cand[512];
    __shared__ unsigned hist[64];
    __shared__ float    redF[16];   __shared__ unsigned redU[16];
    __shared__ float    redF2[16];  __shared__ unsigned redU2[16];
    __shared__ unsigned redM[16];
    __shared__ unsigned capN, cntLowSh, rSh, nCand, fBase;
    __shared__ int      selBin[2];  __shared__ unsigned selBase[2];
    __shared__ int      fBin, fail;
    __shared__ float    vkSh[2];
    __shared__ unsigned loS, hiS;

    if (tid == 0) { capN = 0u; cntLowSh = 0u; fail = 0; }
    __syncthreads();

    const unsigned LOBITS = __float_as_uint(LO_F);

    /* ---------- phase 1: single streaming read ---------- */
    unsigned myLow = 0u, cntHigh = 0u;
    float    sumHigh = 0.0f;
    for (int i = tid; i < COLS / 4; i += THREADS) {
        float4 v = x4[i];
        float vv[4] = { v.x, v.y, v.z, v.w };
        #pragma unroll
        for (int c = 0; c < 4; ++c) {
            float x = vv[c];
            myLow += (x < LO_F) ? 1u : 0u;
            if (x >= HI_F) { sumHigh += x; cntHigh += 1u; }
            bool p = (x >= LO_F) && (x < HI_F);
            unsigned long long m = __ballot(p);
            if (m) {
                int leader = __ffsll((unsigned long long)m) - 1;
                unsigned base = 0u;
                if (lane == leader) base = atomicAdd(&capN, (unsigned)__popcll(m));
                base = __shfl(base, leader);
                if (p) {
                    unsigned idx = base + (unsigned)__popcll(m & ((1ull << lane) - 1ull));
                    if (idx < CAPMAX) cap[idx] = x;
                }
            }
        }
    }
    {
        unsigned wl = wredU(myLow);
        if (lane == 0) atomicAdd(&cntLowSh, wl);
        float    sh = wredF(sumHigh);
        unsigned ch = wredU(cntHigh);
        if (lane == 0) { redF[wid] = sh; redU[wid] = ch; }
    }
    __syncthreads();

    if (tid == 0) {
        if (capN > (unsigned)CAPMAX || cntLowSh > K_RANK ||
            cntLowSh + capN < K_RANK + 2u)
            fail = 1;
        rSh = K_RANK - cntLowSh;
    }
    __syncthreads();

    /* ---------- phase 2: exact select of ranks r, r+1 inside LDS capture ---------- */
    if (!fail) {
        const unsigned cN = capN;
        /* coarse 64-bin histogram over (bits-LOBITS)>>16 (max bin 38) */
        if (tid < 64) hist[tid] = 0u;
        __syncthreads();
        for (unsigned i = tid; i < cN; i += THREADS) {
            unsigned d = __float_as_uint(cap[i]) - LOBITS;
            atomicAdd(&hist[d >> 16], 1u);
        }
        __syncthreads();
        if (wid == 0) {
            unsigned v = hist[lane], incl = v;
            #pragma unroll
            for (int off = 1; off < 64; off <<= 1) {
                unsigned n = __shfl_up(incl, off);
                if (lane >= off) incl += n;
            }
            unsigned excl = incl - v;
            for (int s = 0; s < 2; ++s) {
                unsigned rr = rSh + (unsigned)s;
                if (v && excl <= rr && rr < incl) { selBin[s] = lane; selBase[s] = excl; }
            }
        }
        __syncthreads();

        for (int s = 0; s < 2; ++s) {
            const unsigned rr   = rSh + (unsigned)s;
            const int      binC = selBin[s];
            const unsigned jj   = rr - selBase[s];
            if (tid < 64) hist[tid] = 0u;
            if (tid == 0) nCand = 0u;
            __syncthreads();
            for (unsigned i = tid; i < cN; i += THREADS) {
                unsigned d = __float_as_uint(cap[i]) - LOBITS;
                if ((int)(d >> 16) == binC) atomicAdd(&hist[(d >> 10) & 63u], 1u);
            }
            __syncthreads();
            if (wid == 0) {
                unsigned v = hist[lane], incl = v;
                #pragma unroll
                for (int off = 1; off < 64; off <<= 1) {
                    unsigned n = __shfl_up(incl, off);
                    if (lane >= off) incl += n;
                }
                unsigned excl = incl - v;
                if (v && excl <= jj && jj < incl) { fBin = lane; fBase = excl; }
            }
            __syncthreads();
            const int      binF = fBin;
            const unsigned jk   = jj - fBase;
            for (unsigned i = tid; i < cN; i += THREADS) {
                unsigned d = __float_as_uint(cap[i]) - LOBITS;
                if ((int)(d >> 16) == binC && (int)((d >> 10) & 63u) == binF) {
                    unsigned idx = atomicAdd(&nCand, 1u);
                    if (idx < 512u) cand[idx] = cap[i];
                }
            }
            __syncthreads();
            if (tid == 0 && nCand > 512u) fail = 1;
            __syncthreads();
            {
                unsigned nC = nCand;
                if (nC <= 512u && tid < (int)nC) {
                    float v = cand[tid];
                    unsigned lt = 0u, eq = 0u;
                    for (unsigned i = 0; i < nC; ++i) {
                        float c = cand[i];
                        lt += (c < v) ? 1u : 0u;
                        eq += (c == v) ? 1u : 0u;
                    }
                    if (lt <= jk && jk < lt + eq) vkSh[s] = v;
                }
            }
            __syncthreads();
        }
    }
    __syncthreads();

    /* ---------- fallback: generic 32-step bisection on monotone keys ---------- */
    if (fail) {
        if (tid == 0) { loS = 0u; hiS = 0xFFFFFFFFu; }
        __syncthreads();
        for (int it = 0; it < 32; ++it) {
            unsigned lo = loS, hi = hiS;
            unsigned mid = lo + ((hi - lo) >> 1);
            unsigned c = 0u;
            for (int i = tid; i < COLS / 4; i += THREADS) {
                float4 v = x4[i];
                c += (key_of(v.x) <= mid) ? 1u : 0u;
                c += (key_of(v.y) <= mid) ? 1u : 0u;
                c += (key_of(v.z) <= mid) ? 1u : 0u;
                c += (key_of(v.w) <= mid) ? 1u : 0u;
            }
            c = wredU(c);
            if (lane == 0) redU[wid] = c;
            __syncthreads();
            if (tid == 0) {
                unsigned tot = 0u;
                for (int w = 0; w < 16; ++w) tot += redU[w];
                if (tot >= K_RANK + 1u) hiS = mid; else loS = mid + 1u;
            }
            __syncthreads();
        }
        {
            const unsigned kap = loS;
            unsigned c = 0u, mA = 0xFFFFFFFFu;
            for (int i = tid; i < COLS / 4; i += THREADS) {
                float4 v = x4[i];
                float vv[4] = { v.x, v.y, v.z, v.w };
                #pragma unroll
                for (int cc = 0; cc < 4; ++cc) {
                    unsigned u = key_of(vv[cc]);
                    if (u <= kap) c += 1u; else mA = (u < mA) ? u : mA;
                }
            }
            c = wredU(c); mA = wredMinU(mA);
            if (lane == 0) { redU[wid] = c; redM[wid] = mA; }
            __syncthreads();
            if (tid == 0) {
                unsigned tot = 0u, m = 0xFFFFFFFFu;
                for (int w = 0; w < 16; ++w) { tot += redU[w]; m = (redM[w] < m) ? redM[w] : m; }
                float vk = float_of_key(kap);
                vkSh[0] = vk;
                vkSh[1] = (tot >= K_RANK + 2u) ? vk : float_of_key(m);
            }
            __syncthreads();
        }
    }
    __syncthreads();

    /* ---------- phase 3: selected mean ---------- */
    const float vk  = vkSh[0];
    const float vk1 = vkSh[1];
    const float t   = vk + 0.5f * (vk1 - vk);

    float    s = 0.0f;
    unsigned c = 0u;
    if (!fail) {
        const unsigned cN = capN;
        for (unsigned i = tid; i < cN; i += THREADS) {
            float xv = cap[i];
            if (xv > t) { s += xv; c += 1u; }
        }
    } else {
        for (int i = tid; i < COLS / 4; i += THREADS) {
            float4 v = x4[i];
            float vv[4] = { v.x, v.y, v.z, v.w };
            #pragma unroll
            for (int cc = 0; cc < 4; ++cc) {
                float x = vv[cc];
                if (x > t) { s += x; c += 1u; }
            }
        }
    }
    s = wredF(s); c = wredU(c);
    if (lane == 0) { redF2[wid] = s; redU2[wid] = c; }
    __syncthreads();
    if (tid == 0) {
        float S = 0.0f; unsigned C = 0u;
        for (int w = 0; w < 16; ++w) { S += redF2[w]; C += redU2[w]; }
        if (!fail) {
            for (int w = 0; w < 16; ++w) { S += redF[w]; C += redU[w]; }
        }
        out[row] = S / (float)((C > 0u) ? C : 1u);
    }
}

extern "C" void kernel_launch(void* const* d_in, const int* in_sizes, int n_in,
                              void* d_out, int out_size, void* d_ws, size_t ws_size,
                              hipStream_t stream) {
    const float* X = (const float*)d_in[0];
    float* out = (float*)d_out;
    const int rows = in_sizes[0] / COLS;   /* 512 */
    dtp_kernel<<<rows, THREADS, 0, stream>>>(X, out);
}